// Round 1
// baseline (309.209 us; speedup 1.0000x reference)
//
#include <hip/hip_runtime.h>

typedef unsigned short u16;
typedef __attribute__((ext_vector_type(8))) short short8;   // 8 bf16 = 4 VGPRs
typedef __attribute__((ext_vector_type(4))) float f32x4;
typedef __attribute__((ext_vector_type(4))) int int4v;
typedef __attribute__((ext_vector_type(4))) unsigned short u16x4;

#define NSEQ 8
#define LD 2048
#define LM 512
#define DD 1024
#define HID 1024
#define M1 (NSEQ*LD)   // 16384 input rows
#define M2 (NSEQ*LM)   // 4096 memory rows

__device__ __forceinline__ float bf2f(u16 u) {
    union { unsigned int i; float f; } v; v.i = ((unsigned int)u) << 16; return v.f;
}
__device__ __forceinline__ u16 f2bf(float f) {
    union { float f; unsigned int i; } v; v.f = f;
    unsigned int r = v.i + 0x7fffu + ((v.i >> 16) & 1u);
    return (u16)(r >> 16);
}

// ---- prep: f32 row -> bf16 row + dot(row, w) ----------------------------
__global__ __launch_bounds__(256) void prep_rows(const float* __restrict__ src,
                                                 const float* __restrict__ w,
                                                 u16* __restrict__ dst,
                                                 float* __restrict__ dot) {
    const int row = blockIdx.x, t = threadIdx.x;
    f32x4 v = *(const f32x4*)(src + (size_t)row * DD + t * 4);
    f32x4 wv = *(const f32x4*)(w + t * 4);
    u16x4 o;
    #pragma unroll
    for (int i = 0; i < 4; i++) o[i] = f2bf(v[i]);
    *(u16x4*)(dst + (size_t)row * DD + t * 4) = o;
    float s = v[0]*wv[0] + v[1]*wv[1] + v[2]*wv[2] + v[3]*wv[3];
    #pragma unroll
    for (int off = 32; off; off >>= 1) s += __shfl_down(s, off);
    __shared__ float red[4];
    if ((t & 63) == 0) red[t >> 6] = s;
    __syncthreads();
    if (t == 0) dot[row] = red[0] + red[1] + red[2] + red[3];
}

// ---- transpose f32 [R][C] -> bf16 [C][R], batched over z ----------------
__global__ void transpose_f32_to_bf16(const float* __restrict__ src,
                                      u16* __restrict__ dst,
                                      int R, int C, size_t sn, size_t dn) {
    __shared__ float tile[32][33];
    src += (size_t)blockIdx.z * sn;
    dst += (size_t)blockIdx.z * dn;
    const int c0 = blockIdx.x * 32, r0 = blockIdx.y * 32;
    const int tx = threadIdx.x, ty = threadIdx.y;
    #pragma unroll
    for (int yy = ty; yy < 32; yy += 8)
        tile[yy][tx] = src[(size_t)(r0 + yy) * C + c0 + tx];
    __syncthreads();
    #pragma unroll
    for (int yy = ty; yy < 32; yy += 8)
        dst[(size_t)(c0 + yy) * R + r0 + tx] = f2bf(tile[tx][yy]);
}

// ---- generic 128x128 MFMA GEMM, A[M][K] * B^T where B stored [N][K] -----
// MODE 0: out = acc + bias[col]                       (inp2 / mem2)
// MODE 2: out = acc/32 + idot[row] + mdot[...] - NEG*(1-mask)   (att)
// MODE 3: o1 = acc; writes out blocks 1,2,3 (reads block0 f32, ot)
template <int MODE>
__global__ __launch_bounds__(256) void gemm128(
    const u16* __restrict__ A, const u16* __restrict__ B,
    int lda, int ldb, int K, int rows_per_n, long bstride,
    float* __restrict__ out0, int ldc,
    const float* __restrict__ bias,
    const float* __restrict__ idot, const float* __restrict__ mdot,
    const float* __restrict__ mask, const float* __restrict__ ot) {
    __shared__ __align__(16) u16 lA[128 * 72];
    __shared__ __align__(16) u16 lB[128 * 72];
    const int t = threadIdx.x;
    const int lane = t & 63, wave = t >> 6;
    const int wm = wave >> 1, wn = wave & 1;
    const int lr = lane & 15, kg = lane >> 4;
    const int m0 = blockIdx.x * 128, n0 = blockIdx.y * 128;
    const int nb = m0 / rows_per_n;
    const u16* Bp = B + (size_t)nb * (size_t)bstride;

    f32x4 acc[4][4];
    #pragma unroll
    for (int i = 0; i < 4; i++)
        #pragma unroll
        for (int j = 0; j < 4; j++) acc[i][j] = (f32x4){0.f, 0.f, 0.f, 0.f};

    for (int k0 = 0; k0 < K; k0 += 64) {
        __syncthreads();
        #pragma unroll
        for (int c = 0; c < 4; c++) {
            const int id = t + c * 256;
            const int row = id >> 3, kc = (id & 7) * 8;
            *(int4v*)&lA[row * 72 + kc] =
                *(const int4v*)&A[(size_t)(m0 + row) * lda + k0 + kc];
            *(int4v*)&lB[row * 72 + kc] =
                *(const int4v*)&Bp[(size_t)(n0 + row) * ldb + k0 + kc];
        }
        __syncthreads();
        #pragma unroll
        for (int kk = 0; kk < 2; kk++) {
            short8 af[4], bfr[4];
            #pragma unroll
            for (int i = 0; i < 4; i++)
                af[i] = *(const short8*)&lA[(wm * 64 + i * 16 + lr) * 72 + kk * 32 + kg * 8];
            #pragma unroll
            for (int j = 0; j < 4; j++)
                bfr[j] = *(const short8*)&lB[(wn * 64 + j * 16 + lr) * 72 + kk * 32 + kg * 8];
            #pragma unroll
            for (int i = 0; i < 4; i++)
                #pragma unroll
                for (int j = 0; j < 4; j++)
                    acc[i][j] = __builtin_amdgcn_mfma_f32_16x16x32_bf16(
                        af[i], bfr[j], acc[i][j], 0, 0, 0);
        }
    }

    #pragma unroll
    for (int i = 0; i < 4; i++) {
        #pragma unroll
        for (int j = 0; j < 4; j++) {
            const int col = n0 + wn * 64 + j * 16 + lr;
            #pragma unroll
            for (int r = 0; r < 4; r++) {
                const int row = m0 + wm * 64 + i * 16 + kg * 4 + r;
                float v = acc[i][j][r];
                if constexpr (MODE == 0) {
                    v += bias[col];
                    out0[(size_t)row * ldc + col] = v;
                } else if constexpr (MODE == 2) {
                    v = v * 0.03125f + idot[row] + mdot[nb * LM + col]
                        - 1e30f * (1.0f - mask[nb * LM + col]);
                    out0[(size_t)row * ldc + col] = v;
                } else {
                    const size_t o = (size_t)row * ldc + col;
                    const float o1 = v;
                    const float i2 = out0[o];  // exact f32 inp2 from block 0
                    out0[o + 1024] = o1;
                    out0[o + 2048] = i2 * o1;
                    out0[o + 3072] = ot[nb * HID + col] * o1;
                }
            }
        }
    }
}

// ---- row softmax over Lm=512: att -> P(bf16), rowmax --------------------
__global__ __launch_bounds__(256) void row_softmax(const float* __restrict__ att,
                                                   u16* __restrict__ P,
                                                   float* __restrict__ rowmax) {
    const int row = blockIdx.x, t = threadIdx.x;
    float2 v = ((const float2*)(att + (size_t)row * LM))[t];
    float m = fmaxf(v.x, v.y);
    #pragma unroll
    for (int off = 32; off; off >>= 1) m = fmaxf(m, __shfl_down(m, off));
    __shared__ float sm[4], ss[4];
    if ((t & 63) == 0) sm[t >> 6] = m;
    __syncthreads();
    const float M = fmaxf(fmaxf(sm[0], sm[1]), fmaxf(sm[2], sm[3]));
    float e0 = __expf(v.x - M), e1 = __expf(v.y - M);
    float s = e0 + e1;
    #pragma unroll
    for (int off = 32; off; off >>= 1) s += __shfl_down(s, off);
    if ((t & 63) == 0) ss[t >> 6] = s;
    __syncthreads();
    const float inv = 1.0f / (ss[0] + ss[1] + ss[2] + ss[3]);
    unsigned int packed = (unsigned int)f2bf(e0 * inv) | ((unsigned int)f2bf(e1 * inv) << 16);
    *(unsigned int*)(P + (size_t)row * LM + t * 2) = packed;
    if (t == 0) rowmax[row] = M;
}

// ---- softmax over Ld=2048 rowmax values per n ---------------------------
__global__ __launch_bounds__(256) void w2_softmax(const float* __restrict__ rowmax,
                                                  float* __restrict__ w2) {
    const int n = blockIdx.x, t = threadIdx.x;
    const float* x = rowmax + (size_t)n * LD;
    float v[8];
    float m = -1e30f;
    #pragma unroll
    for (int i = 0; i < 8; i++) { v[i] = x[t + i * 256]; m = fmaxf(m, v[i]); }
    #pragma unroll
    for (int off = 32; off; off >>= 1) m = fmaxf(m, __shfl_down(m, off));
    __shared__ float sm[4], ss[4];
    if ((t & 63) == 0) sm[t >> 6] = m;
    __syncthreads();
    const float M = fmaxf(fmaxf(sm[0], sm[1]), fmaxf(sm[2], sm[3]));
    float s = 0.f;
    #pragma unroll
    for (int i = 0; i < 8; i++) { v[i] = __expf(v[i] - M); s += v[i]; }
    #pragma unroll
    for (int off = 32; off; off >>= 1) s += __shfl_down(s, off);
    if ((t & 63) == 0) ss[t >> 6] = s;
    __syncthreads();
    const float inv = 1.0f / (ss[0] + ss[1] + ss[2] + ss[3]);
    #pragma unroll
    for (int i = 0; i < 8; i++) w2[(size_t)n * LD + t + i * 256] = v[i] * inv;
}

// ---- output_two: partial over l-chunks (deterministic 2-stage) ----------
__global__ __launch_bounds__(256) void out_two_partial(const float* __restrict__ inp2,
                                                       const float* __restrict__ w2,
                                                       float* __restrict__ part) {
    const int h = blockIdx.x * 256 + threadIdx.x;
    const int n = blockIdx.y, lz = blockIdx.z;
    const float* p = inp2 + ((size_t)n * LD + lz * 256) * 4096 + h;  // block0, ldc=4096
    const float* w = w2 + (size_t)n * LD + lz * 256;
    float s = 0.f;
    #pragma unroll 4
    for (int l = 0; l < 256; l++) s += w[l] * p[(size_t)l * 4096];
    part[((size_t)n * 8 + lz) * HID + h] = s;
}

__global__ __launch_bounds__(256) void out_two_final(const float* __restrict__ part,
                                                     float* __restrict__ ot) {
    const int h = blockIdx.x * 256 + threadIdx.x;
    const int n = blockIdx.y;
    float s = 0.f;
    #pragma unroll
    for (int i = 0; i < 8; i++) s += part[((size_t)n * 8 + i) * HID + h];
    ot[(size_t)n * HID + h] = s;
}

extern "C" void kernel_launch(void* const* d_in, const int* in_sizes, int n_in,
                              void* d_out, int out_size, void* d_ws, size_t ws_size,
                              hipStream_t stream) {
    const float* input  = (const float*)d_in[0];
    const float* memory = (const float*)d_in[1];
    const float* mask   = (const float*)d_in[2];
    const float* in1_w  = (const float*)d_in[3];
    const float* mem1_w = (const float*)d_in[4];
    const float* in2_w  = (const float*)d_in[5];
    const float* in2_b  = (const float*)d_in[6];
    const float* mem2_w = (const float*)d_in[7];
    const float* mem2_b = (const float*)d_in[8];

    float* out = (float*)d_out;
    float* outTail = out + (size_t)M1 * 4096;  // mem2 output [N,LM,HID]

    char* ws = (char*)d_ws;
    size_t off = 0;
    auto alloc = [&](size_t bytes) -> void* {
        void* p = ws + off;
        off = (off + bytes + 255) & ~(size_t)255;
        return p;
    };
    u16* input_bf16  = (u16*)alloc((size_t)M1 * DD * 2);      // 33.5 MB
    u16* memory_bf16 = (u16*)alloc((size_t)M2 * DD * 2);      // 8.4 MB
    u16* in2_wt      = (u16*)alloc((size_t)HID * DD * 2);     // 2.1 MB
    u16* mem2_wt     = (u16*)alloc((size_t)HID * DD * 2);     // 2.1 MB
    u16* mem2t       = (u16*)alloc((size_t)NSEQ * HID * LM * 2);  // 8.4 MB
    float* att       = (float*)alloc((size_t)M1 * LM * 4);    // 33.5 MB
    float* idot      = (float*)alloc((size_t)M1 * 4);
    float* mdot      = (float*)alloc((size_t)M2 * 4);
    float* rowmax    = (float*)alloc((size_t)M1 * 4);
    float* w2        = (float*)alloc((size_t)M1 * 4);
    float* ot        = (float*)alloc((size_t)NSEQ * HID * 4);
    float* part      = (float*)alloc((size_t)NSEQ * 8 * HID * 4);
    // P (bf16 softmax weights) aliases input_bf16: input_bf16's last reader
    // (att GEMM) completes before row_softmax writes P. Same size class.
    u16* P = input_bf16;

    // 1) bf16 casts + row dots
    prep_rows<<<M1, 256, 0, stream>>>(input, in1_w, input_bf16, idot);
    prep_rows<<<M2, 256, 0, stream>>>(memory, mem1_w, memory_bf16, mdot);
    // 2) weight transposes -> [HID][DD] bf16
    transpose_f32_to_bf16<<<dim3(32, 32, 1), dim3(32, 8), 0, stream>>>(
        in2_w, in2_wt, DD, HID, 0, 0);
    transpose_f32_to_bf16<<<dim3(32, 32, 1), dim3(32, 8), 0, stream>>>(
        mem2_w, mem2_wt, DD, HID, 0, 0);
    // 3) inp2 = input @ in2_w + b  -> d_out block 0 (ldc 4096)
    gemm128<0><<<dim3(M1 / 128, HID / 128), 256, 0, stream>>>(
        input_bf16, in2_wt, DD, DD, DD, LD, 0L, out, 4096, in2_b,
        nullptr, nullptr, nullptr, nullptr);
    // 4) mem2 = memory @ mem2_w + b -> d_out tail (ldc 1024)
    gemm128<0><<<dim3(M2 / 128, HID / 128), 256, 0, stream>>>(
        memory_bf16, mem2_wt, DD, DD, DD, LM, 0L, outTail, HID, mem2_b,
        nullptr, nullptr, nullptr, nullptr);
    // 5) mem2t[n][h][m] bf16 for PV
    transpose_f32_to_bf16<<<dim3(HID / 32, LM / 32, NSEQ), dim3(32, 8), 0, stream>>>(
        outTail, mem2t, LM, HID, (size_t)LM * HID, (size_t)HID * LM);
    // 6) att = input @ memory^T / 32 + dots + mask
    gemm128<2><<<dim3(M1 / 128, LM / 128), 256, 0, stream>>>(
        input_bf16, memory_bf16, DD, DD, DD, LD, (long)LM * DD, att, LM,
        nullptr, idot, mdot, mask, nullptr);
    // 7) row softmax -> P bf16 (aliases input_bf16), rowmax
    row_softmax<<<M1, 256, 0, stream>>>(att, P, rowmax);
    // 8) weight_two softmax over Ld per n
    w2_softmax<<<NSEQ, 256, 0, stream>>>(rowmax, w2);
    // 9) output_two = sum_l w2[l] * inp2[l,:]  (2-stage deterministic)
    out_two_partial<<<dim3(HID / 256, NSEQ, 8), 256, 0, stream>>>(out, w2, part);
    out_two_final<<<dim3(HID / 256, NSEQ), 256, 0, stream>>>(part, ot);
    // 10) output_one = P @ mem2 ; writes out blocks 1,2,3
    gemm128<3><<<dim3(M1 / 128, HID / 128), 256, 0, stream>>>(
        P, mem2t, LM, LM, LM, LD, (long)HID * LM, out, 4096,
        nullptr, nullptr, nullptr, nullptr, ot);
}